// Round 1
// baseline (1154.372 us; speedup 1.0000x reference)
//
#include <hip/hip_runtime.h>

#define M_TOTAL 65536   // B*T rows
#define DDIM    128     // latent dim (GEMM K)
#define KCODES  1024    // codebook size (GEMM N)
#define NQ      8       // RVQ stages
#define RROWS   64      // rows per block -> 1024 blocks
#define NC      32      // codes per Es chunk (NC=32 keeps LDS at 53 KB -> 3 blocks/CU)
#define NCHUNKS (KCODES / NC)
#define TAU     0.15f   // margin threshold in REF dist units (validated rounds 5-10, absmax 0)

typedef _Float16 half8 __attribute__((ext_vector_type(8)));
typedef float    f32x4 __attribute__((ext_vector_type(4)));

// ---------------- ||e||^2 (verified round-1 semantics) ----------------
__global__ __launch_bounds__(256) void enorm_kernel(const float* __restrict__ embed,
                                                    float* __restrict__ enorm) {
  int c = blockIdx.x * 4 + (threadIdx.x >> 6);
  int lane = threadIdx.x & 63;
  const float* e = embed + (size_t)c * DDIM;
  float v0 = e[lane];
  float v1 = e[lane + 64];
  float s = fmaf(v0, v0, v1 * v1);
  #pragma unroll
  for (int off = 32; off > 0; off >>= 1) s += __shfl_down(s, off);
  if (lane == 0) enorm[c] = s;
}

// ---------------- embed -> f16 plane, row-major ----------------
__global__ __launch_bounds__(256) void esplit16_kernel(const float* __restrict__ embed,
                                                       _Float16* __restrict__ Ef16) {
  size_t base = ((size_t)blockIdx.x * 256 + threadIdx.x) * 8;
  float4 v0 = *(const float4*)(embed + base);
  float4 v1 = *(const float4*)(embed + base + 4);
  half8 h;
  h[0] = (_Float16)v0.x; h[1] = (_Float16)v0.y; h[2] = (_Float16)v0.z; h[3] = (_Float16)v0.w;
  h[4] = (_Float16)v1.x; h[5] = (_Float16)v1.y; h[6] = (_Float16)v1.z; h[7] = (_Float16)v1.w;
  *(half8*)(Ef16 + base) = h;
}

// ---------------- fused 8-stage RVQ: screen + inline exact fixup + resid in LDS ----
// Rows are fully independent across stages, so one block owns 64 rows for ALL 8
// stages: exact f32 residual stays in LDS (never round-trips HBM between stages),
// the exact fixup for margin<=TAU rows runs inline (bit-identical accumulation
// order + "2.0f*acc - enorm" formula of the round-1-verified rvq_fixup, applied
// to the LDS residual, which is arithmetically identical to the old x-sum-of-
// embeds reconstruction: same per-stage f32 subtract chain).
// Epilogue diet vs previous screen: -0.5*||e||^2 folded into the MFMA acc init
// (dist scale halves -> flag threshold TAU*0.5) and second-max via v_med3_f32.
// LDS 53.3 KB -> 3 blocks/CU (launch_bounds(256,3): VGPR cap ~168, no spill).
__global__ __launch_bounds__(256, 3) void rvq_fused(
    const float* __restrict__ x,          // [M_TOTAL][DDIM] f32
    const float* __restrict__ embed,      // [NQ][KCODES][DDIM] f32
    const _Float16* __restrict__ Ef16,    // [NQ][KCODES][DDIM] f16
    const float* __restrict__ enorm,      // [NQ][KCODES]
    int* __restrict__ codes)              // [NQ][M_TOTAL]
{
  // stride 132 floats = 528 B: 16B-aligned rows (ds_*_b128 legal) and 2-way-max
  // bank aliasing on the 16-lane row-strided A-frag reads (bank step 4/row).
  __shared__ __attribute__((aligned(16))) float resid[RROWS][132];        // 33,792 B
  __shared__ __attribute__((aligned(16))) _Float16 Es[2][NC * 136];       // 17,408 B
  __shared__ float redv1[RROWS * 2];
  __shared__ float redv2[RROWS * 2];
  __shared__ int   redi1[RROWS * 2];
  __shared__ int   bcode[RROWS];
  __shared__ float wvv[4];
  __shared__ int   wvi[4];
  __shared__ int   fcnt;
  __shared__ int   frows[RROWS];

  const int tid = threadIdx.x;
  const int wv = tid >> 6;
  const int lane = tid & 63;
  const int l15 = lane & 15;
  const int q = lane >> 4;
  const int rw = wv & 1;          // row-half of the 2x2 wave grid
  const int cw = wv >> 1;         // code-half
  const int row_base = blockIdx.x * RROWS;

  // Es staging indices: 32 codes x 128 k per chunk; 2 half8 per thread, coalesced
  const int s_code = tid >> 4;    // 0..15 (+16 per it)
  const int s_kp   = tid & 15;

  // ---- load x rows into LDS residual (exact f32) ----
  #pragma unroll
  for (int it = 0; it < 8; ++it) {
    int idx = it * 256 + tid;
    int r = idx >> 5, f4 = idx & 31;
    float4 v = *(const float4*)(x + (size_t)(row_base + r) * DDIM + f4 * 4);
    *(float4*)(&resid[r][f4 * 4]) = v;
  }

  for (int st = 0; st < NQ; ++st) {
    const _Float16* EfS = Ef16 + (size_t)st * KCODES * DDIM;
    const float* enS = enorm + (size_t)st * KCODES;
    const float* embS = embed + (size_t)st * KCODES * DDIM;

    if (tid == 0) fcnt = 0;       // any read of previous fcnt is barrier-separated
    __syncthreads();              // residual ready (x load or prev update)

    // ---- A-frags from LDS residual: af[rt][kc], A[m=l15][k=q*8+j] ----
    half8 af[2][4];
    #pragma unroll
    for (int rt = 0; rt < 2; ++rt) {
      const float* pa = &resid[rw * 32 + rt * 16 + l15][0];
      #pragma unroll
      for (int kc = 0; kc < 4; ++kc) {
        float4 x0 = *(const float4*)(pa + kc * 32 + q * 8);
        float4 x1 = *(const float4*)(pa + kc * 32 + q * 8 + 4);
        half8 h;
        h[0] = (_Float16)x0.x; h[1] = (_Float16)x0.y; h[2] = (_Float16)x0.z; h[3] = (_Float16)x0.w;
        h[4] = (_Float16)x1.x; h[5] = (_Float16)x1.y; h[6] = (_Float16)x1.z; h[7] = (_Float16)x1.w;
        af[rt][kc] = h;
      }
    }

    // ---- prologue: stage chunk 0 into Es[0] ----
    half8 pre[2];
    #pragma unroll
    for (int it = 0; it < 2; ++it)
      pre[it] = *(const half8*)(EfS + (size_t)(it * 16 + s_code) * DDIM + s_kp * 8);
    #pragma unroll
    for (int it = 0; it < 2; ++it)
      *(half8*)(&Es[0][(it * 16 + s_code) * 136 + s_kp * 8]) = pre[it];
    __syncthreads();

    float v1[8], v2[8];
    int i1[8];
    #pragma unroll
    for (int sI = 0; sI < 8; ++sI) { v1[sI] = -3.0e38f; v2[sI] = -3.0e38f; i1[sI] = 0x7fffffff; }

    for (int cc = 0; cc < NCHUNKS; ++cc) {
      const int cur = cc & 1;
      if (cc + 1 < NCHUNKS) {     // prefetch next chunk (hides L2 latency behind compute)
        #pragma unroll
        for (int it = 0; it < 2; ++it)
          pre[it] = *(const half8*)(EfS + (size_t)((cc + 1) * NC + it * 16 + s_code) * DDIM + s_kp * 8);
      }
      float enr = enS[cc * NC + cw * 16 + l15];
      float nh = -0.5f * enr;     // folded into acc init: d = dot - ||e||^2/2 = ref_dist/2
      f32x4 acc0 = {nh, nh, nh, nh};
      f32x4 acc1 = {nh, nh, nh, nh};
      #pragma unroll
      for (int kc = 0; kc < 4; ++kc) {
        half8 bf = *(const half8*)(&Es[cur][(cw * 16 + l15) * 136 + kc * 32 + q * 8]);
        acc0 = __builtin_amdgcn_mfma_f32_16x16x32_f16(af[0][kc], bf, acc0, 0, 0, 0);
        acc1 = __builtin_amdgcn_mfma_f32_16x16x32_f16(af[1][kc], bf, acc1, 0, 0, 0);
      }
      // top-2 epilogue, 4 VALU ops/element (med3 second-max; codes ascend ->
      // strict > keeps first occurrence; exact ties -> margin 0 -> fixup decides)
      const int cgi = cc * NC + cw * 16 + l15;
      #pragma unroll
      for (int reg = 0; reg < 4; ++reg) {
        float d0 = acc0[reg];
        v2[reg] = __builtin_amdgcn_fmed3f(d0, v1[reg], v2[reg]);
        if (d0 > v1[reg]) i1[reg] = cgi;
        v1[reg] = fmaxf(v1[reg], d0);
        float d1 = acc1[reg];
        v2[4 + reg] = __builtin_amdgcn_fmed3f(d1, v1[4 + reg], v2[4 + reg]);
        if (d1 > v1[4 + reg]) i1[4 + reg] = cgi;
        v1[4 + reg] = fmaxf(v1[4 + reg], d1);
      }
      if (cc + 1 < NCHUNKS) {
        #pragma unroll
        for (int it = 0; it < 2; ++it)
          *(half8*)(&Es[cur ^ 1][(it * 16 + s_code) * 136 + s_kp * 8]) = pre[it];
      }
      __syncthreads();            // 1 barrier/chunk (dbuf; verified structure)
    }

    // ---- merge top-2 across the 16 l15-lanes sharing each row (disjoint codes) ----
    #pragma unroll
    for (int sI = 0; sI < 8; ++sI) {
      #pragma unroll
      for (int off = 1; off < 16; off <<= 1) {
        float ov1 = __shfl_xor(v1[sI], off);
        int   oi1 = __shfl_xor(i1[sI], off);
        float ov2 = __shfl_xor(v2[sI], off);
        if (ov1 > v1[sI] || (ov1 == v1[sI] && oi1 < i1[sI])) {
          float nv2 = fmaxf(v1[sI], ov2);
          v1[sI] = ov1; i1[sI] = oi1; v2[sI] = nv2;
        } else {
          v2[sI] = fmaxf(v2[sI], ov1);
        }
      }
    }
    if (l15 == 0) {
      #pragma unroll
      for (int sI = 0; sI < 8; ++sI) {
        int row = rw * 32 + (sI >> 2) * 16 + q * 4 + (sI & 3);
        redv1[row * 2 + cw] = v1[sI];
        redi1[row * 2 + cw] = i1[sI];
        redv2[row * 2 + cw] = v2[sI];
      }
    }
    __syncthreads();

    // ---- final per-row merge (2 code-groups), flag into block-local list ----
    if (tid < RROWS) {
      float a1 = redv1[tid * 2], a2 = redv2[tid * 2];
      int ai = redi1[tid * 2];
      float b1v = redv1[tid * 2 + 1], b2v = redv2[tid * 2 + 1];
      int bi = redi1[tid * 2 + 1];
      float bv1, bv2; int bidx;
      if (b1v > a1 || (b1v == a1 && bi < ai)) {
        bv1 = b1v; bidx = bi; bv2 = fmaxf(a1, b2v);
      } else {
        bv1 = a1; bidx = ai; bv2 = fmaxf(b1v, a2);
      }
      bcode[tid] = bidx;
      if (bv1 - bv2 <= TAU * 0.5f) {       // dist scale is ref/2
        int p = atomicAdd(&fcnt, 1);
        frows[p] = tid;
      }
    }
    __syncthreads();

    // ---- inline exact fixup (round-1-verified fp32 semantics, vs LDS residual) ----
    const int nf = fcnt;
    for (int fi = 0; fi < nf; ++fi) {
      const int r = frows[fi];
      float a0 = 0.f, a1 = 0.f, a2 = 0.f, a3 = 0.f;
      const float* eb = embS + (size_t)tid * 4 * DDIM;   // codes 4t..4t+3
      #pragma unroll 4
      for (int k4 = 0; k4 < 32; ++k4) {
        float4 rv = *(const float4*)(&resid[r][k4 * 4]); // LDS broadcast
        float4 e0 = *(const float4*)(eb + 0 * DDIM + k4 * 4);
        float4 e1 = *(const float4*)(eb + 1 * DDIM + k4 * 4);
        float4 e2 = *(const float4*)(eb + 2 * DDIM + k4 * 4);
        float4 e3 = *(const float4*)(eb + 3 * DDIM + k4 * 4);
        a0 = fmaf(rv.x, e0.x, a0); a0 = fmaf(rv.y, e0.y, a0); a0 = fmaf(rv.z, e0.z, a0); a0 = fmaf(rv.w, e0.w, a0);
        a1 = fmaf(rv.x, e1.x, a1); a1 = fmaf(rv.y, e1.y, a1); a1 = fmaf(rv.z, e1.z, a1); a1 = fmaf(rv.w, e1.w, a1);
        a2 = fmaf(rv.x, e2.x, a2); a2 = fmaf(rv.y, e2.y, a2); a2 = fmaf(rv.z, e2.z, a2); a2 = fmaf(rv.w, e2.w, a2);
        a3 = fmaf(rv.x, e3.x, a3); a3 = fmaf(rv.y, e3.y, a3); a3 = fmaf(rv.z, e3.z, a3); a3 = fmaf(rv.w, e3.w, a3);
      }
      float bv = -3.0e38f; int bi = 0x7fffffff;
      {  // ascending jc -> first occurrence (lowest index) kept; exact formula preserved
        float dd0 = 2.0f * a0 - enS[tid * 4 + 0]; if (dd0 > bv) { bv = dd0; bi = tid * 4 + 0; }
        float dd1 = 2.0f * a1 - enS[tid * 4 + 1]; if (dd1 > bv) { bv = dd1; bi = tid * 4 + 1; }
        float dd2 = 2.0f * a2 - enS[tid * 4 + 2]; if (dd2 > bv) { bv = dd2; bi = tid * 4 + 2; }
        float dd3 = 2.0f * a3 - enS[tid * 4 + 3]; if (dd3 > bv) { bv = dd3; bi = tid * 4 + 3; }
      }
      #pragma unroll
      for (int off = 32; off > 0; off >>= 1) {
        float o = __shfl_down(bv, off);
        int oi = __shfl_down(bi, off);
        if (o > bv || (o == bv && oi < bi)) { bv = o; bi = oi; }
      }
      if (lane == 0) { wvv[wv] = bv; wvi[wv] = bi; }
      __syncthreads();
      if (tid == 0) {
        float fb = wvv[0]; int fbi = wvi[0];
        #pragma unroll
        for (int w = 1; w < 4; ++w) {
          if (wvv[w] > fb || (wvv[w] == fb && wvi[w] < fbi)) { fb = wvv[w]; fbi = wvi[w]; }
        }
        bcode[r] = fbi;
      }
      __syncthreads();            // bcode visible; wvv reusable next fi
    }

    // ---- codes out + exact f32 residual update in LDS (after fixup: final codes) ----
    if (tid < RROWS) codes[(size_t)st * M_TOTAL + row_base + tid] = bcode[tid];
    if (st < NQ - 1) {
      #pragma unroll
      for (int it = 0; it < 8; ++it) {
        int idx = it * 256 + tid;
        int r = idx >> 5, f4 = idx & 31;
        float4 e = *(const float4*)(embS + (size_t)bcode[r] * DDIM + f4 * 4);
        float4 cu = *(const float4*)(&resid[r][f4 * 4]);
        float4 o;
        o.x = cu.x - e.x; o.y = cu.y - e.y; o.z = cu.z - e.z; o.w = cu.w - e.w;
        *(float4*)(&resid[r][f4 * 4]) = o;   // owner-exclusive, no race
      }
    }
    // next stage's first __syncthreads() orders these writes vs A-frag reads
  }
}

// ================= fallback: round-2 verified exact-fp32 kernel =================
#define F_NCHUNK  256
#define F_KC      16
#define F_AS_STRIDE 68
#define F_ES_STRIDE 260

__global__ __launch_bounds__(256, 3) void rvq_stage_kernel(
    const float* __restrict__ rin, float* __restrict__ rout,
    const float* __restrict__ embed, const float* __restrict__ enorm,
    int* __restrict__ codes)
{
  __shared__ float smem[DDIM * F_AS_STRIDE + F_KC * F_ES_STRIDE + F_NCHUNK];
  float* As  = smem;
  float* Es  = smem + DDIM * F_AS_STRIDE;
  float* Ens = Es + F_KC * F_ES_STRIDE;
  float* red_v = Es;
  int*   red_i = (int*)(Es + 64 * 33);
  int*   bcode = (int*)(Es + 2 * 64 * 33);

  const int tid = threadIdx.x;
  const int tx = tid & 31;
  const int ty = tid >> 5;
  const int row_base = blockIdx.x * 64;

  #pragma unroll
  for (int it = 0; it < 8; ++it) {
    int idx = it * 256 + tid;
    int r = idx >> 5, f4 = idx & 31;
    float4 v = *(const float4*)(rin + (size_t)(row_base + r) * DDIM + f4 * 4);
    As[(4 * f4 + 0) * F_AS_STRIDE + r] = v.x;
    As[(4 * f4 + 1) * F_AS_STRIDE + r] = v.y;
    As[(4 * f4 + 2) * F_AS_STRIDE + r] = v.z;
    As[(4 * f4 + 3) * F_AS_STRIDE + r] = v.w;
  }

  float best[8]; int bidx[8];
  #pragma unroll
  for (int i = 0; i < 8; ++i) { best[i] = -3.0e38f; bidx[i] = 0x7fffffff; }

  for (int nc = 0; nc < KCODES / F_NCHUNK; ++nc) {
    float acc[8][8];
    #pragma unroll
    for (int i = 0; i < 8; ++i)
      #pragma unroll
      for (int j = 0; j < 8; ++j) acc[i][j] = 0.0f;

    for (int kc = 0; kc < DDIM / F_KC; ++kc) {
      __syncthreads();
      #pragma unroll
      for (int it = 0; it < 4; ++it) {
        int idx = it * 256 + tid;
        int c = idx >> 2, f4 = idx & 3;
        float4 v = *(const float4*)(embed + (size_t)(nc * F_NCHUNK + c) * DDIM + kc * F_KC + f4 * 4);
        Es[(4 * f4 + 0) * F_ES_STRIDE + c] = v.x;
        Es[(4 * f4 + 1) * F_ES_STRIDE + c] = v.y;
        Es[(4 * f4 + 2) * F_ES_STRIDE + c] = v.z;
        Es[(4 * f4 + 3) * F_ES_STRIDE + c] = v.w;
      }
      if (kc == 0) Ens[tid] = enorm[nc * F_NCHUNK + tid];
      __syncthreads();

      const float* pa = As + kc * F_KC * F_AS_STRIDE + ty * 8;
      const float* pe = Es + 4 * tx;
      #pragma unroll 4
      for (int k = 0; k < F_KC; ++k) {
        float4 a0 = *(const float4*)(pa + k * F_AS_STRIDE);
        float4 a1 = *(const float4*)(pa + k * F_AS_STRIDE + 4);
        float4 e0 = *(const float4*)(pe + k * F_ES_STRIDE);
        float4 e1 = *(const float4*)(pe + k * F_ES_STRIDE + 128);
        float aa[8] = {a0.x, a0.y, a0.z, a0.w, a1.x, a1.y, a1.z, a1.w};
        float ee[8] = {e0.x, e0.y, e0.z, e0.w, e1.x, e1.y, e1.z, e1.w};
        #pragma unroll
        for (int i = 0; i < 8; ++i)
          #pragma unroll
          for (int j = 0; j < 8; ++j)
            acc[i][j] = fmaf(aa[i], ee[j], acc[i][j]);
      }
    }

    #pragma unroll
    for (int j = 0; j < 8; ++j) {
      int c_local = (j < 4) ? (4 * tx + j) : (128 + 4 * tx + (j - 4));
      float en = Ens[c_local];
      int cg = nc * F_NCHUNK + c_local;
      #pragma unroll
      for (int i = 0; i < 8; ++i) {
        float dist = 2.0f * acc[i][j] - en;
        if (dist > best[i] || (dist == best[i] && cg < bidx[i])) { best[i] = dist; bidx[i] = cg; }
      }
    }
  }

  __syncthreads();
  #pragma unroll
  for (int i = 0; i < 8; ++i) {
    red_v[(ty * 8 + i) * 33 + tx] = best[i];
    red_i[(ty * 8 + i) * 33 + tx] = bidx[i];
  }
  __syncthreads();
  if (tid < 64) {
    float bv = red_v[tid * 33]; int bi = red_i[tid * 33];
    #pragma unroll
    for (int t = 1; t < 32; ++t) {
      float v = red_v[tid * 33 + t]; int ix = red_i[tid * 33 + t];
      if (v > bv || (v == bv && ix < bi)) { bv = v; bi = ix; }
    }
    codes[row_base + tid] = bi;
    bcode[tid] = bi;
  }
  __syncthreads();
  #pragma unroll
  for (int it = 0; it < 32; ++it) {
    int idx = it * 256 + tid;
    int r = idx >> 7, d = idx & 127;
    float e = embed[(size_t)bcode[r] * DDIM + d];
    rout[(size_t)(row_base + r) * DDIM + d] = As[d * F_AS_STRIDE + r] - e;
  }
}

extern "C" void kernel_launch(void* const* d_in, const int* in_sizes, int n_in,
                              void* d_out, int out_size, void* d_ws, size_t ws_size,
                              hipStream_t stream) {
  (void)in_sizes; (void)n_in; (void)out_size;
  const float* x = (const float*)d_in[0];
  const float* embed = (const float*)d_in[1];
  int* codes = (int*)d_out;

  const size_t E16_BYTES = (size_t)NQ * KCODES * DDIM * 2;        // 2 MB f16 codebook
  const size_t EN_BYTES  = (size_t)NQ * KCODES * 4;               // 32 KB
  const size_t need = E16_BYTES + EN_BYTES + 256;

  if (ws_size >= need) {
    char* w = (char*)d_ws;
    _Float16* Ef16 = (_Float16*)w;     w += E16_BYTES;
    float* enorm   = (float*)w;

    enorm_kernel<<<dim3(NQ * KCODES / 4), dim3(256), 0, stream>>>(embed, enorm);
    esplit16_kernel<<<dim3(NQ * KCODES * DDIM / 8 / 256), dim3(256), 0, stream>>>(embed, Ef16);
    rvq_fused<<<dim3(M_TOTAL / RROWS), dim3(256), 0, stream>>>(x, embed, Ef16, enorm, codes);
  } else {
    // fallback: verified round-2 exact-fp32 path
    const size_t resid_elems = (size_t)M_TOTAL * DDIM;
    const bool ws_ok = ws_size >= (resid_elems + (size_t)NQ * KCODES) * sizeof(float);
    float* resid = ws_ok ? (float*)d_ws : (float*)d_in[0];
    float* enorm = ws_ok ? ((float*)d_ws + resid_elems) : (float*)d_ws;

    enorm_kernel<<<dim3(NQ * KCODES / 4), dim3(256), 0, stream>>>(embed, enorm);
    for (int q = 0; q < NQ; ++q) {
      const float* rin = (q == 0) ? x : resid;
      rvq_stage_kernel<<<dim3(M_TOTAL / 64), dim3(256), 0, stream>>>(
          rin, resid, embed + (size_t)q * KCODES * DDIM,
          enorm + (size_t)q * KCODES, codes + (size_t)q * M_TOTAL);
    }
  }
}

// Round 2
// 773.372 us; speedup vs baseline: 1.4926x; 1.4926x over previous
//
#include <hip/hip_runtime.h>

#define M_TOTAL 65536   // B*T rows
#define DDIM    128     // latent dim (GEMM K)
#define KCODES  1024    // codebook size (GEMM N)
#define NQ      8       // RVQ stages
#define RROWS   64      // rows per block -> 1024 blocks (exactly 4/CU resident)
#define NC      64      // codes per Es chunk (round-0 geometry)
#define NCHUNKS (KCODES / NC)          // 16
#define CHUNK_B (NC * DDIM * 2)        // 16384 bytes per chunk (f16)
#define TAU     0.15f   // margin threshold in REF dist units (validated; screen dist = ref/2)
#define FB      8       // fixup rows per batched codebook scan

typedef _Float16 half8 __attribute__((ext_vector_type(8)));
typedef float    f32x4 __attribute__((ext_vector_type(4)));

// direct global->LDS copy, 16 B per lane; LDS dest is wave-uniform base + lane*16
__device__ __forceinline__ void gld_lds16(const void* g, void* l) {
  __builtin_amdgcn_global_load_lds(
      (const __attribute__((address_space(1))) unsigned int*)g,
      (__attribute__((address_space(3))) unsigned int*)l, 16, 0, 0);
}

// ---------------- ||e||^2 (verified round-1 semantics) ----------------
__global__ __launch_bounds__(256) void enorm_kernel(const float* __restrict__ embed,
                                                    float* __restrict__ enorm) {
  int c = blockIdx.x * 4 + (threadIdx.x >> 6);
  int lane = threadIdx.x & 63;
  const float* e = embed + (size_t)c * DDIM;
  float v0 = e[lane];
  float v1 = e[lane + 64];
  float s = fmaf(v0, v0, v1 * v1);
  #pragma unroll
  for (int off = 32; off > 0; off >>= 1) s += __shfl_down(s, off);
  if (lane == 0) enorm[c] = s;
}

// ---------------- embed -> f16 plane, PRE-SWIZZLED for linear global_load_lds ----
// 16B block j of code c stored at block position j ^ (c&7). After a linear
// global->LDS copy (stride 256 B rows), the screen's 16-lane row-strided
// ds_read_b128 lands on 8 distinct bank stripes x 2 lanes = conflict-free.
__global__ __launch_bounds__(256) void esplit16_kernel(const float* __restrict__ embed,
                                                       _Float16* __restrict__ Ef16) {
  unsigned u = blockIdx.x * 256 + threadIdx.x;          // half8 index: ((s*1024+c)*16+j)
  size_t src = (size_t)u * 8;
  float4 v0 = *(const float4*)(embed + src);
  float4 v1 = *(const float4*)(embed + src + 4);
  half8 h;
  h[0] = (_Float16)v0.x; h[1] = (_Float16)v0.y; h[2] = (_Float16)v0.z; h[3] = (_Float16)v0.w;
  h[4] = (_Float16)v1.x; h[5] = (_Float16)v1.y; h[6] = (_Float16)v1.z; h[7] = (_Float16)v1.w;
  unsigned row = u >> 4;                                // s*1024 + c
  unsigned j   = u & 15;
  size_t dst = (size_t)row * 128 + 8 * (j ^ (row & 7)); // (row&7) == (c&7)
  *(half8*)(Ef16 + dst) = h;
}

// ---------------- fused 8-stage RVQ ----------------
// Block owns 64 rows for all 8 stages. Residual lives in GLOBAL workspace
// (block-private 32 KB slice, L2-hot; same-CU write-through + L1-invalidate
// makes intra-block RAW across __syncthreads safe). LDS budget ~39.9 KB ->
// 4 blocks/CU, 16 waves/CU (round-0 screen occupancy). Es staged via
// global_load_lds (dbuf, 1 barrier/chunk, full-chunk latency window).
// Inline fixup: batched (<=FB rows per scan), codebook chunks staged into the
// Es union COALESCED, exact round-1-validated arithmetic (same fmaf chain
// order, 2.0f*acc-enorm, lowest-index tie-breaks).
__global__ __launch_bounds__(256, 4) void rvq_fused(
    const float* __restrict__ x,          // [M_TOTAL][DDIM] f32
    float* __restrict__ resid,            // [M_TOTAL][DDIM] f32 workspace
    const float* __restrict__ embed,      // [NQ][KCODES][DDIM] f32
    const _Float16* __restrict__ Ef16,    // [NQ][KCODES][DDIM] f16, pre-swizzled
    const float* __restrict__ enorm,      // [NQ][KCODES]
    int* __restrict__ codes)              // [NQ][M_TOTAL]
{
  // Union: screen Es dbuf (2 x 16384 B) / fixup f32 chunk [64][132] (33792 B)
  __shared__ __attribute__((aligned(16))) char EsU[64 * 132 * 4];
  __shared__ float rowbuf[FB][DDIM];
  __shared__ float redv1[RROWS * 2];
  __shared__ float redv2[RROWS * 2];
  __shared__ int   redi1[RROWS * 2];
  __shared__ int   bcode[RROWS];
  __shared__ int   frows[RROWS];
  __shared__ int   fcnt;

  char* const esB = EsU;
  float (*FS)[132] = (float(*)[132])EsU;

  const int tid = threadIdx.x;
  const int wv = tid >> 6;
  const int lane = tid & 63;
  const int l15 = lane & 15;
  const int q = lane >> 4;
  const int rw = wv & 1;          // row-half of the 2x2 wave grid
  const int cw = wv >> 1;         // code-half
  const int row_base = blockIdx.x * RROWS;
  const int rx = cw * 32 + l15;   // B-frag row within chunk (ct=0); ct=1 adds 16
  const int xr = rx & 7;          // bank swizzle key (rows rx and rx+16 share it)

  for (int st = 0; st < NQ; ++st) {
    const _Float16* EfS = Ef16 + (size_t)st * KCODES * DDIM;
    const float* enS = enorm + (size_t)st * KCODES;
    const float* embS = embed + (size_t)st * KCODES * DDIM;
    const float* rin = (st == 0) ? x : resid;

    if (tid == 0) fcnt = 0;       // consumed only after many barriers

    // ---- A-frags from global rin (round-0 screen pattern, L2-hot) ----
    half8 af[2][4];
    #pragma unroll
    for (int rt = 0; rt < 2; ++rt) {
      const float* pa = rin + (size_t)(row_base + rw * 32 + rt * 16 + l15) * DDIM;
      #pragma unroll
      for (int kc = 0; kc < 4; ++kc) {
        float4 x0 = *(const float4*)(pa + kc * 32 + q * 8);
        float4 x1 = *(const float4*)(pa + kc * 32 + q * 8 + 4);
        half8 h;
        h[0] = (_Float16)x0.x; h[1] = (_Float16)x0.y; h[2] = (_Float16)x0.z; h[3] = (_Float16)x0.w;
        h[4] = (_Float16)x1.x; h[5] = (_Float16)x1.y; h[6] = (_Float16)x1.z; h[7] = (_Float16)x1.w;
        af[rt][kc] = h;
      }
    }

    // ---- prologue: stage chunk 0 into buffer 0 (linear copy == swizzled layout) ----
    {
      const char* g = (const char*)EfS;
      #pragma unroll
      for (int it = 0; it < 4; ++it) {
        const int off = it * 4096 + wv * 1024;
        gld_lds16(g + off + lane * 16, esB + off);
      }
    }
    __syncthreads();              // drains gll vmcnt; chunk 0 ready

    float v1[8], v2[8];
    int i1[8];
    #pragma unroll
    for (int sI = 0; sI < 8; ++sI) { v1[sI] = -3.0e38f; v2[sI] = -3.0e38f; i1[sI] = 0x7fffffff; }

    for (int cc = 0; cc < NCHUNKS; ++cc) {
      const int cur = cc & 1;
      if (cc + 1 < NCHUNKS) {     // prefetch next chunk into other buffer (full-chunk window)
        const char* g = (const char*)EfS + (size_t)(cc + 1) * CHUNK_B;
        char* l = esB + (cur ^ 1) * CHUNK_B;
        #pragma unroll
        for (int it = 0; it < 4; ++it) {
          const int off = it * 4096 + wv * 1024;
          gld_lds16(g + off + lane * 16, l + off);
        }
      }
      float enr0 = enS[cc * NC + cw * 32 + l15];
      float enr1 = enS[cc * NC + cw * 32 + 16 + l15];
      float nh0 = -0.5f * enr0;   // folded: d = dot - ||e||^2/2 = ref_dist/2 (validated r1)
      float nh1 = -0.5f * enr1;
      f32x4 acc[2][2];
      #pragma unroll
      for (int rt = 0; rt < 2; ++rt) {
        acc[rt][0] = (f32x4){nh0, nh0, nh0, nh0};
        acc[rt][1] = (f32x4){nh1, nh1, nh1, nh1};
      }

      const char* eb = esB + cur * CHUNK_B;
      #pragma unroll
      for (int kc = 0; kc < 4; ++kc) {
        const int jswz = 16 * ((kc * 4 + q) ^ xr);
        half8 bf0 = *(const half8*)(eb + rx * 256 + jswz);
        half8 bf1 = *(const half8*)(eb + (rx + 16) * 256 + jswz);
        #pragma unroll
        for (int rt = 0; rt < 2; ++rt) {
          acc[rt][0] = __builtin_amdgcn_mfma_f32_16x16x32_f16(af[rt][kc], bf0, acc[rt][0], 0, 0, 0);
          acc[rt][1] = __builtin_amdgcn_mfma_f32_16x16x32_f16(af[rt][kc], bf1, acc[rt][1], 0, 0, 0);
        }
      }

      // top-2 epilogue (med3 second-max; codes ascend -> strict > keeps first occurrence)
      #pragma unroll
      for (int ct = 0; ct < 2; ++ct) {
        const int cgi = cc * NC + cw * 32 + ct * 16 + l15;
        #pragma unroll
        for (int rt = 0; rt < 2; ++rt)
          #pragma unroll
          for (int reg = 0; reg < 4; ++reg) {
            float d = acc[rt][ct][reg];
            int s = rt * 4 + reg;
            v2[s] = __builtin_amdgcn_fmed3f(d, v1[s], v2[s]);
            if (d > v1[s]) i1[s] = cgi;
            v1[s] = fmaxf(v1[s], d);
          }
      }
      __syncthreads();            // next buffer staged + this buffer reusable
    }

    // ---- merge top-2 across the 16 l15-lanes sharing each row (disjoint codes) ----
    #pragma unroll
    for (int sI = 0; sI < 8; ++sI) {
      #pragma unroll
      for (int off = 1; off < 16; off <<= 1) {
        float ov1 = __shfl_xor(v1[sI], off);
        int   oi1 = __shfl_xor(i1[sI], off);
        float ov2 = __shfl_xor(v2[sI], off);
        if (ov1 > v1[sI] || (ov1 == v1[sI] && oi1 < i1[sI])) {
          float nv2 = fmaxf(v1[sI], ov2);
          v1[sI] = ov1; i1[sI] = oi1; v2[sI] = nv2;
        } else {
          v2[sI] = fmaxf(v2[sI], ov1);
        }
      }
    }
    if (l15 == 0) {
      #pragma unroll
      for (int sI = 0; sI < 8; ++sI) {
        int row = rw * 32 + (sI >> 2) * 16 + q * 4 + (sI & 3);
        redv1[row * 2 + cw] = v1[sI];
        redi1[row * 2 + cw] = i1[sI];
        redv2[row * 2 + cw] = v2[sI];
      }
    }
    __syncthreads();

    // ---- final per-row merge (2 code-groups), flag into block-local list ----
    if (tid < RROWS) {
      float a1 = redv1[tid * 2], a2 = redv2[tid * 2];
      int ai = redi1[tid * 2];
      float b1v = redv1[tid * 2 + 1], b2v = redv2[tid * 2 + 1];
      int bi = redi1[tid * 2 + 1];
      float bv1, bv2; int bidx;
      if (b1v > a1 || (b1v == a1 && bi < ai)) {
        bv1 = b1v; bidx = bi; bv2 = fmaxf(a1, b2v);
      } else {
        bv1 = a1; bidx = ai; bv2 = fmaxf(b1v, a2);
      }
      bcode[tid] = bidx;
      if (bv1 - bv2 <= TAU * 0.5f) {       // screen dist scale is ref/2
        int p = atomicAdd(&fcnt, 1);
        frows[p] = tid;
      }
    }
    __syncthreads();

    // ---- batched inline exact fixup (round-1-validated arithmetic) ----
    // <=FB rows share ONE coalesced codebook scan; wave w owns batch rows {w, w+4};
    // lane owns code ch*64+lane per chunk. Per-(code,row) fmaf chain order, the
    // 2.0f*acc-enorm formula, and lowest-index tie-breaks are unchanged.
    const int nf = fcnt;
    for (int b0 = 0; b0 < nf; b0 += FB) {
      const int nb = min(FB, nf - b0);
      for (int j0 = 0; j0 < nb; j0 += 2) {
        int j = j0 + (tid >> 7);
        int d = tid & 127;
        if (j < nb) rowbuf[j][d] = rin[(size_t)(row_base + frows[b0 + j]) * DDIM + d];
      }
      __syncthreads();

      const int ja = wv;          // rows this wave handles
      const int jb = wv + 4;
      float bva = -3.0e38f, bvb = -3.0e38f;
      int   bia = 0x7fffffff, bib = 0x7fffffff;

      for (int ch = 0; ch < 16; ++ch) {
        // stage 64 codes x 128 f32, coalesced global reads, padded LDS rows
        #pragma unroll
        for (int it = 0; it < 8; ++it) {
          int idx = it * 256 + tid;
          int c = idx >> 5, f4 = idx & 31;
          *(float4*)(&FS[c][f4 * 4]) =
              *(const float4*)(embS + (size_t)(ch * 64 + c) * DDIM + f4 * 4);
        }
        __syncthreads();

        const int c = ch * 64 + lane;
        const float en = enS[c];
        if (ja < nb) {
          float a = 0.f;
          #pragma unroll 4
          for (int k4 = 0; k4 < 32; ++k4) {
            float4 rv = *(const float4*)(&rowbuf[ja][k4 * 4]);
            float4 e4 = *(const float4*)(&FS[lane][k4 * 4]);
            a = fmaf(rv.x, e4.x, a); a = fmaf(rv.y, e4.y, a);
            a = fmaf(rv.z, e4.z, a); a = fmaf(rv.w, e4.w, a);
          }
          float dd = 2.0f * a - en;
          if (dd > bva) { bva = dd; bia = c; }   // c ascends with ch -> keeps lowest
        }
        if (jb < nb) {
          float a = 0.f;
          #pragma unroll 4
          for (int k4 = 0; k4 < 32; ++k4) {
            float4 rv = *(const float4*)(&rowbuf[jb][k4 * 4]);
            float4 e4 = *(const float4*)(&FS[lane][k4 * 4]);
            a = fmaf(rv.x, e4.x, a); a = fmaf(rv.y, e4.y, a);
            a = fmaf(rv.z, e4.z, a); a = fmaf(rv.w, e4.w, a);
          }
          float dd = 2.0f * a - en;
          if (dd > bvb) { bvb = dd; bib = c; }
        }
        __syncthreads();          // FS reusable next chunk
      }

      // wave-level argmax (lowest-index tie-break), one row per active slot
      if (ja < nb) {
        float bv = bva; int bi = bia;
        #pragma unroll
        for (int off = 32; off > 0; off >>= 1) {
          float o = __shfl_down(bv, off);
          int oi = __shfl_down(bi, off);
          if (o > bv || (o == bv && oi < bi)) { bv = o; bi = oi; }
        }
        if (lane == 0) bcode[frows[b0 + ja]] = bi;
      }
      if (jb < nb) {
        float bv = bvb; int bi = bib;
        #pragma unroll
        for (int off = 32; off > 0; off >>= 1) {
          float o = __shfl_down(bv, off);
          int oi = __shfl_down(bi, off);
          if (o > bv || (o == bv && oi < bi)) { bv = o; bi = oi; }
        }
        if (lane == 0) bcode[frows[b0 + jb]] = bi;
      }
      __syncthreads();            // bcode visible; rowbuf reusable
    }

    // ---- codes out + exact f32 residual update (final codes; in-place safe:
    //      block owns rows exclusively, same-CU L1 invalidated by write-through) ----
    if (tid < RROWS) codes[(size_t)st * M_TOTAL + row_base + tid] = bcode[tid];
    if (st < NQ - 1) {
      #pragma unroll
      for (int it = 0; it < 8; ++it) {
        int idx = it * 256 + tid;
        int r = idx >> 5, f4 = idx & 31;
        float4 e = *(const float4*)(embS + (size_t)bcode[r] * DDIM + f4 * 4);
        float4 a = *(const float4*)(rin + (size_t)(row_base + r) * DDIM + f4 * 4);
        float4 o;
        o.x = a.x - e.x; o.y = a.y - e.y; o.z = a.z - e.z; o.w = a.w - e.w;
        *(float4*)(resid + (size_t)(row_base + r) * DDIM + f4 * 4) = o;
      }
    }
    __syncthreads();              // resid writes + bcode lifetime vs next stage
  }
}

// ================= fallback: round-2 verified exact-fp32 kernel =================
#define F_NCHUNK  256
#define F_KC      16
#define F_AS_STRIDE 68
#define F_ES_STRIDE 260

__global__ __launch_bounds__(256, 3) void rvq_stage_kernel(
    const float* __restrict__ rin, float* __restrict__ rout,
    const float* __restrict__ embed, const float* __restrict__ enorm,
    int* __restrict__ codes)
{
  __shared__ float smem[DDIM * F_AS_STRIDE + F_KC * F_ES_STRIDE + F_NCHUNK];
  float* As  = smem;
  float* Es  = smem + DDIM * F_AS_STRIDE;
  float* Ens = Es + F_KC * F_ES_STRIDE;
  float* red_v = Es;
  int*   red_i = (int*)(Es + 64 * 33);
  int*   bcode = (int*)(Es + 2 * 64 * 33);

  const int tid = threadIdx.x;
  const int tx = tid & 31;
  const int ty = tid >> 5;
  const int row_base = blockIdx.x * 64;

  #pragma unroll
  for (int it = 0; it < 8; ++it) {
    int idx = it * 256 + tid;
    int r = idx >> 5, f4 = idx & 31;
    float4 v = *(const float4*)(rin + (size_t)(row_base + r) * DDIM + f4 * 4);
    As[(4 * f4 + 0) * F_AS_STRIDE + r] = v.x;
    As[(4 * f4 + 1) * F_AS_STRIDE + r] = v.y;
    As[(4 * f4 + 2) * F_AS_STRIDE + r] = v.z;
    As[(4 * f4 + 3) * F_AS_STRIDE + r] = v.w;
  }

  float best[8]; int bidx[8];
  #pragma unroll
  for (int i = 0; i < 8; ++i) { best[i] = -3.0e38f; bidx[i] = 0x7fffffff; }

  for (int nc = 0; nc < KCODES / F_NCHUNK; ++nc) {
    float acc[8][8];
    #pragma unroll
    for (int i = 0; i < 8; ++i)
      #pragma unroll
      for (int j = 0; j < 8; ++j) acc[i][j] = 0.0f;

    for (int kc = 0; kc < DDIM / F_KC; ++kc) {
      __syncthreads();
      #pragma unroll
      for (int it = 0; it < 4; ++it) {
        int idx = it * 256 + tid;
        int c = idx >> 2, f4 = idx & 3;
        float4 v = *(const float4*)(embed + (size_t)(nc * F_NCHUNK + c) * DDIM + kc * F_KC + f4 * 4);
        Es[(4 * f4 + 0) * F_ES_STRIDE + c] = v.x;
        Es[(4 * f4 + 1) * F_ES_STRIDE + c] = v.y;
        Es[(4 * f4 + 2) * F_ES_STRIDE + c] = v.z;
        Es[(4 * f4 + 3) * F_ES_STRIDE + c] = v.w;
      }
      if (kc == 0) Ens[tid] = enorm[nc * F_NCHUNK + tid];
      __syncthreads();

      const float* pa = As + kc * F_KC * F_AS_STRIDE + ty * 8;
      const float* pe = Es + 4 * tx;
      #pragma unroll 4
      for (int k = 0; k < F_KC; ++k) {
        float4 a0 = *(const float4*)(pa + k * F_AS_STRIDE);
        float4 a1 = *(const float4*)(pa + k * F_AS_STRIDE + 4);
        float4 e0 = *(const float4*)(pe + k * F_ES_STRIDE);
        float4 e1 = *(const float4*)(pe + k * F_ES_STRIDE + 128);
        float aa[8] = {a0.x, a0.y, a0.z, a0.w, a1.x, a1.y, a1.z, a1.w};
        float ee[8] = {e0.x, e0.y, e0.z, e0.w, e1.x, e1.y, e1.z, e1.w};
        #pragma unroll
        for (int i = 0; i < 8; ++i)
          #pragma unroll
          for (int j = 0; j < 8; ++j)
            acc[i][j] = fmaf(aa[i], ee[j], acc[i][j]);
      }
    }

    #pragma unroll
    for (int j = 0; j < 8; ++j) {
      int c_local = (j < 4) ? (4 * tx + j) : (128 + 4 * tx + (j - 4));
      float en = Ens[c_local];
      int cg = nc * F_NCHUNK + c_local;
      #pragma unroll
      for (int i = 0; i < 8; ++i) {
        float dist = 2.0f * acc[i][j] - en;
        if (dist > best[i] || (dist == best[i] && cg < bidx[i])) { best[i] = dist; bidx[i] = cg; }
      }
    }
  }

  __syncthreads();
  #pragma unroll
  for (int i = 0; i < 8; ++i) {
    red_v[(ty * 8 + i) * 33 + tx] = best[i];
    red_i[(ty * 8 + i) * 33 + tx] = bidx[i];
  }
  __syncthreads();
  if (tid < 64) {
    float bv = red_v[tid * 33]; int bi = red_i[tid * 33];
    #pragma unroll
    for (int t = 1; t < 32; ++t) {
      float v = red_v[tid * 33 + t]; int ix = red_i[tid * 33 + t];
      if (v > bv || (v == bv && ix < bi)) { bv = v; bi = ix; }
    }
    codes[row_base + tid] = bi;
    bcode[tid] = bi;
  }
  __syncthreads();
  #pragma unroll
  for (int it = 0; it < 32; ++it) {
    int idx = it * 256 + tid;
    int r = idx >> 7, d = idx & 127;
    float e = embed[(size_t)bcode[r] * DDIM + d];
    rout[(size_t)(row_base + r) * DDIM + d] = As[d * F_AS_STRIDE + r] - e;
  }
}

extern "C" void kernel_launch(void* const* d_in, const int* in_sizes, int n_in,
                              void* d_out, int out_size, void* d_ws, size_t ws_size,
                              hipStream_t stream) {
  (void)in_sizes; (void)n_in; (void)out_size;
  const float* x = (const float*)d_in[0];
  const float* embed = (const float*)d_in[1];
  int* codes = (int*)d_out;

  const size_t R_BYTES   = (size_t)M_TOTAL * DDIM * 4;            // 32 MB f32 residual
  const size_t E16_BYTES = (size_t)NQ * KCODES * DDIM * 2;        // 2 MB f16 codebook
  const size_t EN_BYTES  = (size_t)NQ * KCODES * 4;               // 32 KB
  const size_t need = R_BYTES + E16_BYTES + EN_BYTES + 256;

  if (ws_size >= need) {
    char* w = (char*)d_ws;
    float* resid   = (float*)w;        w += R_BYTES;
    _Float16* Ef16 = (_Float16*)w;     w += E16_BYTES;
    float* enorm   = (float*)w;

    enorm_kernel<<<dim3(NQ * KCODES / 4), dim3(256), 0, stream>>>(embed, enorm);
    esplit16_kernel<<<dim3(NQ * KCODES * DDIM / 8 / 256), dim3(256), 0, stream>>>(embed, Ef16);
    rvq_fused<<<dim3(M_TOTAL / RROWS), dim3(256), 0, stream>>>(
        x, resid, embed, Ef16, enorm, codes);
  } else {
    // fallback: verified round-2 exact-fp32 path
    const size_t resid_elems = (size_t)M_TOTAL * DDIM;
    const bool ws_ok = ws_size >= (resid_elems + (size_t)NQ * KCODES) * sizeof(float);
    float* resid = ws_ok ? (float*)d_ws : (float*)d_in[0];
    float* enorm = ws_ok ? ((float*)d_ws + resid_elems) : (float*)d_ws;

    enorm_kernel<<<dim3(NQ * KCODES / 4), dim3(256), 0, stream>>>(embed, enorm);
    for (int q = 0; q < NQ; ++q) {
      const float* rin = (q == 0) ? x : resid;
      rvq_stage_kernel<<<dim3(M_TOTAL / 64), dim3(256), 0, stream>>>(
          rin, resid, embed + (size_t)q * KCODES * DDIM,
          enorm + (size_t)q * KCODES, codes + (size_t)q * M_TOTAL);
    }
  }
}